// Round 1
// baseline (117.351 us; speedup 1.0000x reference)
//
#include <hip/hip_runtime.h>
#include <cstddef>

#define EPS 1e-5f

constexpr int NG  = 8192;   // genes
constexpr int HID = 32768;  // hidden (= NG*4)
constexpr int NTF = 1024;   // TFs
constexpr int B   = 256;    // batch

// round-to-nearest-even f32 -> bf16 bits (no NaN inputs in this problem)
static __device__ __forceinline__ unsigned short f2bf(float v) {
    union { float f; unsigned u; } a; a.f = v;
    unsigned r = a.u + 0x7fffu + ((a.u >> 16) & 1u);
    return (unsigned short)(r >> 16);
}

// ---------------------------------------------------------------------------
// Kernel 1: fused  sparse-L1 -> relu -> BN1 -> sparse-L2(4x4 blockdiag) -> relu
// Writes relu(h2) in BATCH-TILE-MAJOR transposed layout:
//   h2b[bt][c][r]  (bt = b>>6 in [0,4), r = b&63)  -> 128 B per (bt, col)
// i.e. byte offset ((bt*HID + c)*64 + r)*2.  One cacheline per (bt,col), and
// a gene's 4 columns are 512 B contiguous within a batch tile -> fused3 can
// do fully-sequential 1 KB wave loads and sweep batch tiles for L2 locality.
// Also emits per-column (mean2, invstd2) so BN2 folds into layer-3 weights.
// ---------------------------------------------------------------------------
__global__ __launch_bounds__(256) void fused12(
    const float* __restrict__ x,       // [B][NG]
    const float* __restrict__ w1,      // [HID]
    const float* __restrict__ b1,      // [HID]
    const float* __restrict__ w2,      // [HID*4]
    const float* __restrict__ b2,      // [HID]
    unsigned short* __restrict__ h2b,  // [4][HID][64] bf16 bits
    float* __restrict__ m2g,           // [HID]
    float* __restrict__ inv2g)         // [HID]
{
    const int lane  = threadIdx.x & 63;   // column within block tile
    const int slice = threadIdx.x >> 6;   // batch tile (64 rows)
    const int c     = (blockIdx.x << 6) + lane;  // global hidden column
    const int g     = c >> 2;             // gene
    const int b0    = slice << 6;

    __shared__ float redA[4][64], redB[4][64];
    __shared__ float m1s[64], inv1s[64];

    const float w1c = w1[c], b1c = b1[c];
    const float* xp = x + (size_t)b0 * NG + g;

    // ---- phase A: BN1 stats for column c over this thread's 64 rows ----
    float s = 0.f, s2 = 0.f;
    #pragma unroll 8
    for (int i = 0; i < 64; ++i) {
        float h = fmaxf(fmaf(w1c, xp[(size_t)i * NG], b1c), 0.f);
        s += h;
        s2 = fmaf(h, h, s2);
    }
    redA[slice][lane] = s;
    redB[slice][lane] = s2;
    __syncthreads();
    if (slice == 0) {
        float S  = redA[0][lane] + redA[1][lane] + redA[2][lane] + redA[3][lane];
        float S2 = redB[0][lane] + redB[1][lane] + redB[2][lane] + redB[3][lane];
        float m  = S * (1.f / 256.f);
        float v  = fmaf(-m, m, S2 * (1.f / 256.f));
        m1s[lane]   = m;
        inv1s[lane] = rsqrtf(v + EPS);
    }
    __syncthreads();

    // ---- fold BN1 into the 4x4 block weights ----
    const int lbase = lane & ~3;   // first column of my gene in LDS tile
    const int gbase = g << 2;      // first global column of my gene
    float w1j[4], b1j[4], w2s[4];
    float bconst = b2[c];
    #pragma unroll
    for (int j = 0; j < 4; ++j) {
        w1j[j] = w1[gbase + j];
        b1j[j] = b1[gbase + j];
        float wv = w2[(c << 2) + j] * inv1s[lbase + j];
        w2s[j] = wv;
        bconst = fmaf(-wv, m1s[lbase + j], bconst);
    }

    // ---- phase B: recompute h1, folded L2, relu, BN2 stats, bf16 store ----
    float t2s = 0.f, t2s2 = 0.f;
    unsigned short* op = h2b + ((size_t)slice * HID + c) * 64;  // 128 B line
    for (int i0 = 0; i0 < 64; i0 += 4) {
        ushort4 pk;
        unsigned short* pp = (unsigned short*)&pk;
        #pragma unroll
        for (int u = 0; u < 4; ++u) {
            float v = xp[(size_t)(i0 + u) * NG];
            float acc = bconst;
            #pragma unroll
            for (int j = 0; j < 4; ++j) {
                float r = fmaxf(fmaf(w1j[j], v, b1j[j]), 0.f);
                acc = fmaf(w2s[j], r, acc);
            }
            float r2 = fmaxf(acc, 0.f);
            t2s += r2;
            t2s2 = fmaf(r2, r2, t2s2);
            pp[u] = f2bf(r2);
        }
        *(ushort4*)(op + i0) = pk;   // 8 B store, aligned
    }

    __syncthreads();                 // phase-A reads of redA/redB done
    redA[slice][lane] = t2s;
    redB[slice][lane] = t2s2;
    __syncthreads();
    if (slice == 0) {
        float S  = redA[0][lane] + redA[1][lane] + redA[2][lane] + redA[3][lane];
        float S2 = redB[0][lane] + redB[1][lane] + redB[2][lane] + redB[3][lane];
        float m  = S * (1.f / 256.f);
        float v  = fmaf(-m, m, S2 * (1.f / 256.f));
        m2g[c]   = m;
        inv2g[c] = rsqrtf(v + EPS);
    }
}

// ---------------------------------------------------------------------------
// Kernel 2: layer 3 gather-dot (BN2 folded into weights) + BN3 + output.
// Block = one TF t (1024 blocks -> 4/CU, all co-resident).
//
// Batch-tile sweep: loop bt = 0..3 over 64-row tiles. All blocks sweep in the
// same order, so the live working set is one 4.19 MB slice of h2b ~ one XCD
// L2 -> repeat gathers within an XCD hit L2 instead of streaming from L3.
//
// Gene-contiguous loads: the TF's 64 genes each own 512 B contiguous per
// tile (4 cols x 128 B).  Round r: 8 genes x 32 uint4-slots; thread tid ->
// gene jb*8 + (tid>>5), byte (tid&31)*16 within the gene's 512 B.  A wave's
// 64 lanes cover 1 KB fully sequential.  8 rows/lane -> 8 accumulators.
// 32 x 16B loads/thread total (was 64 x 8B).
// ---------------------------------------------------------------------------
__global__ __launch_bounds__(256) void fused3(
    const unsigned short* __restrict__ h2,  // [4][HID][64] bf16 bits
    const float* __restrict__ m2g,          // [HID]
    const float* __restrict__ inv2g,        // [HID]
    const float* __restrict__ w3,           // [NTF*256]
    const float* __restrict__ b3,           // [NTF]
    const int*   __restrict__ cols3,        // [NTF*256]
    float* __restrict__ out)                // [B][NTF]
{
    const int t   = blockIdx.x;
    const int tid = threadIdx.x;

    __shared__ float wls[256];
    __shared__ int   als[64];               // byte offset of gene base (gene*512)
    __shared__ float wred[4], rs[4], rs2[4];
    __shared__ float accq[32][64];          // [gene/col-group][row-in-tile]
    __shared__ float red2[4][64];
    __shared__ float zs[256];               // pre-bias dot per batch row

    // fold BN2 into w3; accumulate bias correction (tid = edge index here)
    int   col = cols3[(t << 8) + tid];
    float wv  = w3[(t << 8) + tid] * inv2g[col];
    wls[tid]  = wv;
    if (tid < 64) als[tid] = cols3[(t << 8) + (tid << 2)] << 7;  // gene*4*128
    float bp  = wv * m2g[col];
    #pragma unroll
    for (int o = 32; o > 0; o >>= 1) bp += __shfl_xor(bp, o);
    if ((tid & 63) == 0) wred[tid >> 6] = bp;
    __syncthreads();

    const char* h2c  = (const char*)h2;
    const int   lrow = (tid & 7) << 3;      // first of my 8 rows in the tile

    for (int bt = 0; bt < 4; ++bt) {
        float a0=0.f,a1=0.f,a2=0.f,a3=0.f,a4=0.f,a5=0.f,a6=0.f,a7=0.f;
        const char* bpt = h2c + (size_t)bt * ((size_t)HID * 128) + ((tid & 31) << 4);
        #pragma unroll
        for (int jb = 0; jb < 8; ++jb) {
            const int   j = (jb << 3) + (tid >> 5);
            const float w = wls[(jb << 5) + (tid >> 3)];
            const uint4 u = *(const uint4*)(bpt + als[j]);   // 8 rows, 16 B
            union { unsigned v; float f; } p0,p1,p2,p3,p4,p5,p6,p7;
            p0.v = u.x << 16; p1.v = u.x & 0xffff0000u;
            p2.v = u.y << 16; p3.v = u.y & 0xffff0000u;
            p4.v = u.z << 16; p5.v = u.z & 0xffff0000u;
            p6.v = u.w << 16; p7.v = u.w & 0xffff0000u;
            a0 = fmaf(w, p0.f, a0); a1 = fmaf(w, p1.f, a1);
            a2 = fmaf(w, p2.f, a2); a3 = fmaf(w, p3.f, a3);
            a4 = fmaf(w, p4.f, a4); a5 = fmaf(w, p5.f, a5);
            a6 = fmaf(w, p6.f, a6); a7 = fmaf(w, p7.f, a7);
        }
        __syncthreads();   // prev tile's accq/red2 consumers done
        *(float4*)&accq[tid >> 3][lrow]     = make_float4(a0, a1, a2, a3);
        *(float4*)&accq[tid >> 3][lrow + 4] = make_float4(a4, a5, a6, a7);
        __syncthreads();
        {
            const int r = tid & 63, gq = tid >> 6;
            float p = 0.f;
            #pragma unroll
            for (int i = 0; i < 8; ++i) p += accq[(gq << 3) + i][r];
            red2[gq][r] = p;
        }
        __syncthreads();
        if (tid < 64)
            zs[(bt << 6) + tid] = red2[0][tid] + red2[1][tid]
                                + red2[2][tid] + red2[3][tid];
    }
    __syncthreads();

    // BN3 over the 256 batch rows (tid = batch row now)
    const float zbias = b3[t] - (wred[0] + wred[1] + wred[2] + wred[3]);
    float z = zs[tid] + zbias;

    float s = z, s2 = z * z;
    #pragma unroll
    for (int o = 32; o > 0; o >>= 1) {
        s  += __shfl_xor(s, o);
        s2 += __shfl_xor(s2, o);
    }
    if ((tid & 63) == 0) { rs[tid >> 6] = s; rs2[tid >> 6] = s2; }
    __syncthreads();
    float S  = rs[0] + rs[1] + rs[2] + rs[3];
    float S2 = rs2[0] + rs2[1] + rs2[2] + rs2[3];
    float m  = S * (1.f / 256.f);
    float v  = fmaf(-m, m, S2 * (1.f / 256.f));
    float invs = rsqrtf(v + EPS);
    out[(size_t)tid * NTF + t] = (z - m) * invs;
}

// ---------------------------------------------------------------------------
extern "C" void kernel_launch(void* const* d_in, const int* in_sizes, int n_in,
                              void* d_out, int out_size, void* d_ws, size_t ws_size,
                              hipStream_t stream) {
    const float* x   = (const float*)d_in[0];
    const float* w1  = (const float*)d_in[1];
    const float* b1  = (const float*)d_in[2];
    const float* w2  = (const float*)d_in[3];
    const float* b2  = (const float*)d_in[4];
    const float* w3  = (const float*)d_in[5];
    const float* b3  = (const float*)d_in[6];
    const int* cols3 = (const int*)d_in[12];
    float* out = (float*)d_out;

    // workspace: h2b [4][HID][64] bf16 (16.8 MB) + m2 [HID] + inv2 [HID] f32
    unsigned short* h2b = (unsigned short*)d_ws;
    float* m2g   = (float*)(h2b + (size_t)HID * B);
    float* inv2g = m2g + HID;

    fused12<<<HID / 64, 256, 0, stream>>>(x, w1, b1, w2, b2, h2b, m2g, inv2g);
    fused3<<<NTF, 256, 0, stream>>>(h2b, m2g, inv2g, w3, b3, cols3, out);
}

// Round 2
// 114.821 us; speedup vs baseline: 1.0220x; 1.0220x over previous
//
#include <hip/hip_runtime.h>
#include <cstddef>

#define EPS 1e-5f

constexpr int NG  = 8192;   // genes
constexpr int HID = 32768;  // hidden (= NG*4)
constexpr int NTF = 1024;   // TFs
constexpr int B   = 256;    // batch

// round-to-nearest-even f32 -> bf16 bits (no NaN inputs in this problem)
static __device__ __forceinline__ unsigned short f2bf(float v) {
    union { float f; unsigned u; } a; a.f = v;
    unsigned r = a.u + 0x7fffu + ((a.u >> 16) & 1u);
    return (unsigned short)(r >> 16);
}

// ---------------------------------------------------------------------------
// Kernel 1: fused  sparse-L1 -> relu -> BN1 -> sparse-L2(4x4 blockdiag) -> relu
// v2: single x pass (x cached in 32 VGPRs), 1024 blocks (4/CU, 4 waves/SIMD),
// per-thread load depth 32 (was 128 over two passes at 2 waves/SIMD).
//
// Block = 32 hidden columns x 8 batch-slices of 32 rows.
// Writes relu(h2) in batch-tile-major layout h2b[bt][c][r] (bt=b>>6, r=b&63):
// 128 B per (bt,col); a gene's 4 cols are 512 B contiguous per batch tile.
// Also emits per-column (mean2, invstd2) so BN2 folds into layer-3 weights.
// ---------------------------------------------------------------------------
__global__ __launch_bounds__(256) void fused12(
    const float* __restrict__ x,       // [B][NG]
    const float* __restrict__ w1,      // [HID]
    const float* __restrict__ b1,      // [HID]
    const float* __restrict__ w2,      // [HID*4]
    const float* __restrict__ b2,      // [HID]
    unsigned short* __restrict__ h2b,  // [4][HID][64] bf16 bits
    float* __restrict__ m2g,           // [HID]
    float* __restrict__ inv2g)         // [HID]
{
    const int lane  = threadIdx.x & 31;   // column within 32-col tile
    const int slice = threadIdx.x >> 5;   // 8 slices x 32 rows
    const int c     = (blockIdx.x << 5) + lane;  // global hidden column
    const int g     = c >> 2;             // gene
    const int r0    = slice << 5;         // first batch row of my slice

    __shared__ float redA[8][32], redB[8][32];
    __shared__ float m1s[32], inv1s[32];

    const float w1c = w1[c], b1c = b1[c];
    const float* xp = x + (size_t)r0 * NG + g;

    // ---- phase A: load x once into registers; BN1 stats for column c ----
    float xv[32];
    float s = 0.f, s2 = 0.f;
    #pragma unroll
    for (int i = 0; i < 32; ++i) {
        float v = xp[(size_t)i * NG];
        xv[i] = v;
        float h = fmaxf(fmaf(w1c, v, b1c), 0.f);
        s += h;
        s2 = fmaf(h, h, s2);
    }
    redA[slice][lane] = s;
    redB[slice][lane] = s2;
    __syncthreads();
    if (threadIdx.x < 32) {
        float S = 0.f, S2 = 0.f;
        #pragma unroll
        for (int k = 0; k < 8; ++k) { S += redA[k][threadIdx.x]; S2 += redB[k][threadIdx.x]; }
        float m = S * (1.f / 256.f);
        float v = fmaf(-m, m, S2 * (1.f / 256.f));
        m1s[threadIdx.x]   = m;
        inv1s[threadIdx.x] = rsqrtf(v + EPS);
    }
    __syncthreads();

    // ---- fold BN1 into the 4x4 block weights ----
    const int lbase = lane & ~3;   // first column of my gene in LDS tile
    const int gbase = g << 2;      // first global column of my gene
    float w1j[4], b1j[4], w2s[4];
    float bconst = b2[c];
    #pragma unroll
    for (int j = 0; j < 4; ++j) {
        w1j[j] = w1[gbase + j];
        b1j[j] = b1[gbase + j];
        float wv = w2[(c << 2) + j] * inv1s[lbase + j];
        w2s[j] = wv;
        bconst = fmaf(-wv, m1s[lbase + j], bconst);
    }

    // ---- phase B: recompute h1 from registers, folded L2, relu, BN2 stats ----
    float t2s = 0.f, t2s2 = 0.f;
    const int bt = slice >> 1;            // 64-row batch tile
    const int rr = (slice & 1) << 5;      // row offset within tile (0 or 32)
    unsigned short* op = h2b + ((size_t)bt * HID + c) * 64 + rr;
    for (int i0 = 0; i0 < 32; i0 += 4) {
        ushort4 pk;
        unsigned short* pp = (unsigned short*)&pk;
        #pragma unroll
        for (int u = 0; u < 4; ++u) {
            float v = xv[i0 + u];
            float acc = bconst;
            #pragma unroll
            for (int j = 0; j < 4; ++j) {
                float r = fmaxf(fmaf(w1j[j], v, b1j[j]), 0.f);
                acc = fmaf(w2s[j], r, acc);
            }
            float r2 = fmaxf(acc, 0.f);
            t2s += r2;
            t2s2 = fmaf(r2, r2, t2s2);
            pp[u] = f2bf(r2);
        }
        *(ushort4*)(op + i0) = pk;   // 8 B store, aligned
    }

    __syncthreads();                 // phase-A reads of redA/redB done
    redA[slice][lane] = t2s;
    redB[slice][lane] = t2s2;
    __syncthreads();
    if (threadIdx.x < 32) {
        float S = 0.f, S2 = 0.f;
        #pragma unroll
        for (int k = 0; k < 8; ++k) { S += redA[k][threadIdx.x]; S2 += redB[k][threadIdx.x]; }
        float m = S * (1.f / 256.f);
        float v = fmaf(-m, m, S2 * (1.f / 256.f));
        const int cw = (blockIdx.x << 5) + threadIdx.x;
        m2g[cw]   = m;
        inv2g[cw] = rsqrtf(v + EPS);
    }
}

// ---------------------------------------------------------------------------
// Kernel 2: layer 3 gather-dot (BN2 folded into weights) + BN3 + output.
// (unchanged from round 1 — measured neutral vs round 0, kept for its lower
// instruction count)
// ---------------------------------------------------------------------------
__global__ __launch_bounds__(256) void fused3(
    const unsigned short* __restrict__ h2,  // [4][HID][64] bf16 bits
    const float* __restrict__ m2g,          // [HID]
    const float* __restrict__ inv2g,        // [HID]
    const float* __restrict__ w3,           // [NTF*256]
    const float* __restrict__ b3,           // [NTF]
    const int*   __restrict__ cols3,        // [NTF*256]
    float* __restrict__ out)                // [B][NTF]
{
    const int t   = blockIdx.x;
    const int tid = threadIdx.x;

    __shared__ float wls[256];
    __shared__ int   als[64];               // byte offset of gene base (gene*512)
    __shared__ float wred[4], rs[4], rs2[4];
    __shared__ float accq[32][64];          // [gene/col-group][row-in-tile]
    __shared__ float red2[4][64];
    __shared__ float zs[256];               // pre-bias dot per batch row

    // fold BN2 into w3; accumulate bias correction (tid = edge index here)
    int   col = cols3[(t << 8) + tid];
    float wv  = w3[(t << 8) + tid] * inv2g[col];
    wls[tid]  = wv;
    if (tid < 64) als[tid] = cols3[(t << 8) + (tid << 2)] << 7;  // gene*4*128
    float bp  = wv * m2g[col];
    #pragma unroll
    for (int o = 32; o > 0; o >>= 1) bp += __shfl_xor(bp, o);
    if ((tid & 63) == 0) wred[tid >> 6] = bp;
    __syncthreads();

    const char* h2c  = (const char*)h2;
    const int   lrow = (tid & 7) << 3;      // first of my 8 rows in the tile

    for (int bt = 0; bt < 4; ++bt) {
        float a0=0.f,a1=0.f,a2=0.f,a3=0.f,a4=0.f,a5=0.f,a6=0.f,a7=0.f;
        const char* bpt = h2c + (size_t)bt * ((size_t)HID * 128) + ((tid & 31) << 4);
        #pragma unroll
        for (int jb = 0; jb < 8; ++jb) {
            const int   j = (jb << 3) + (tid >> 5);
            const float w = wls[(jb << 5) + (tid >> 3)];
            const uint4 u = *(const uint4*)(bpt + als[j]);   // 8 rows, 16 B
            union { unsigned v; float f; } p0,p1,p2,p3,p4,p5,p6,p7;
            p0.v = u.x << 16; p1.v = u.x & 0xffff0000u;
            p2.v = u.y << 16; p3.v = u.y & 0xffff0000u;
            p4.v = u.z << 16; p5.v = u.z & 0xffff0000u;
            p6.v = u.w << 16; p7.v = u.w & 0xffff0000u;
            a0 = fmaf(w, p0.f, a0); a1 = fmaf(w, p1.f, a1);
            a2 = fmaf(w, p2.f, a2); a3 = fmaf(w, p3.f, a3);
            a4 = fmaf(w, p4.f, a4); a5 = fmaf(w, p5.f, a5);
            a6 = fmaf(w, p6.f, a6); a7 = fmaf(w, p7.f, a7);
        }
        __syncthreads();   // prev tile's accq/red2 consumers done
        *(float4*)&accq[tid >> 3][lrow]     = make_float4(a0, a1, a2, a3);
        *(float4*)&accq[tid >> 3][lrow + 4] = make_float4(a4, a5, a6, a7);
        __syncthreads();
        {
            const int r = tid & 63, gq = tid >> 6;
            float p = 0.f;
            #pragma unroll
            for (int i = 0; i < 8; ++i) p += accq[(gq << 3) + i][r];
            red2[gq][r] = p;
        }
        __syncthreads();
        if (tid < 64)
            zs[(bt << 6) + tid] = red2[0][tid] + red2[1][tid]
                                + red2[2][tid] + red2[3][tid];
    }
    __syncthreads();

    // BN3 over the 256 batch rows (tid = batch row now)
    const float zbias = b3[t] - (wred[0] + wred[1] + wred[2] + wred[3]);
    float z = zs[tid] + zbias;

    float s = z, s2 = z * z;
    #pragma unroll
    for (int o = 32; o > 0; o >>= 1) {
        s  += __shfl_xor(s, o);
        s2 += __shfl_xor(s2, o);
    }
    if ((tid & 63) == 0) { rs[tid >> 6] = s; rs2[tid >> 6] = s2; }
    __syncthreads();
    float S  = rs[0] + rs[1] + rs[2] + rs[3];
    float S2 = rs2[0] + rs2[1] + rs2[2] + rs2[3];
    float m  = S * (1.f / 256.f);
    float v  = fmaf(-m, m, S2 * (1.f / 256.f));
    float invs = rsqrtf(v + EPS);
    out[(size_t)tid * NTF + t] = (z - m) * invs;
}

// ---------------------------------------------------------------------------
extern "C" void kernel_launch(void* const* d_in, const int* in_sizes, int n_in,
                              void* d_out, int out_size, void* d_ws, size_t ws_size,
                              hipStream_t stream) {
    const float* x   = (const float*)d_in[0];
    const float* w1  = (const float*)d_in[1];
    const float* b1  = (const float*)d_in[2];
    const float* w2  = (const float*)d_in[3];
    const float* b2  = (const float*)d_in[4];
    const float* w3  = (const float*)d_in[5];
    const float* b3  = (const float*)d_in[6];
    const int* cols3 = (const int*)d_in[12];
    float* out = (float*)d_out;

    // workspace: h2b [4][HID][64] bf16 (16.8 MB) + m2 [HID] + inv2 [HID] f32
    unsigned short* h2b = (unsigned short*)d_ws;
    float* m2g   = (float*)(h2b + (size_t)HID * B);
    float* inv2g = m2g + HID;

    fused12<<<HID / 32, 256, 0, stream>>>(x, w1, b1, w2, b2, h2b, m2g, inv2g);
    fused3<<<NTF, 256, 0, stream>>>(h2b, m2g, inv2g, w3, b3, cols3, out);
}